// Round 1
// baseline (930.984 us; speedup 1.0000x reference)
//
#include <hip/hip_runtime.h>
#include <hip/hip_bf16.h>

// Swin block: C=180, NH=6, HD=30, WS=8, SS=4, N=64, B=16, H=W=128, nW=256.
typedef short s16x8 __attribute__((ext_vector_type(8)));
typedef float f32x4 __attribute__((ext_vector_type(4)));

__device__ __forceinline__ short f2bf(float f) {
    __bf16 h = (__bf16)f;
    return __builtin_bit_cast(short, h);
}

__device__ __forceinline__ f32x4 mfma16(s16x8 a, s16x8 b, f32x4 c) {
    return __builtin_amdgcn_mfma_f32_16x16x32_bf16(a, b, c, 0, 0, 0);
}

// ---------------- workspace layout (bytes) ----------------
// Wqkv  bf16 [544][192]  @ 0        (208896)
// Wproj bf16 [192][192]  @ 208896   (73728)
// Wfc1  bf16 [368][192]  @ 282624   (141312)
// Wfc2  bf16 [192][384]  @ 423936   (147456)
// battn f32  [6][64][64] @ 571392   (98304)   total 669696

__global__ void k_prep(const float* __restrict__ qkv_w, const float* __restrict__ proj_w,
                       const float* __restrict__ fc1_w, const float* __restrict__ fc2_w,
                       const float* __restrict__ rpb,
                       short* __restrict__ Wqkv, short* __restrict__ Wproj,
                       short* __restrict__ Wfc1, short* __restrict__ Wfc2,
                       float* __restrict__ battn) {
    int gt = blockIdx.x * 256 + threadIdx.x;
    int stride = gridDim.x * 256;
    for (int idx = gt; idx < 544 * 192; idx += stride) {
        int rr = idx / 192, kk = idx - rr * 192;
        Wqkv[idx] = (rr < 540 && kk < 180) ? f2bf(qkv_w[rr * 180 + kk]) : (short)0;
    }
    for (int idx = gt; idx < 192 * 192; idx += stride) {
        int rr = idx / 192, kk = idx - rr * 192;
        Wproj[idx] = (rr < 180 && kk < 180) ? f2bf(proj_w[rr * 180 + kk]) : (short)0;
    }
    for (int idx = gt; idx < 368 * 192; idx += stride) {
        int rr = idx / 192, kk = idx - rr * 192;
        Wfc1[idx] = (rr < 360 && kk < 180) ? f2bf(fc1_w[rr * 180 + kk]) : (short)0;
    }
    for (int idx = gt; idx < 192 * 384; idx += stride) {
        int rr = idx / 384, kk = idx - rr * 384;
        Wfc2[idx] = (rr < 180 && kk < 360) ? f2bf(fc2_w[rr * 360 + kk]) : (short)0;
    }
    for (int idx = gt; idx < 6 * 64 * 64; idx += stride) {
        int hh = idx >> 12, n = (idx >> 6) & 63, m = idx & 63;
        int r1 = n >> 3, c1 = n & 7, r2 = m >> 3, c2 = m & 7;
        int ridx = (r1 - r2 + 7) * 15 + (c1 - c2 + 7);
        battn[idx] = rpb[ridx * 6 + hh];
    }
}

// ---------------- fused window-attention kernel ----------------
// One block (256 thr = 4 waves) per window. LDS carve:
//  xln  bf16 [64][200] @ 0       (25600)  reused as attn_out
//  qsm  bf16 [6][64][40] @ 25600 (30720)
//  ksm  bf16 [6][64][40] @ 56320 (30720)
//  vsT  bf16 [6][32][72] @ 87040 (27648)
//  Pb   bf16 [4][16][72] @ 114688 (9216)    total 123904
//  pout f32  [64][184]   @ 25600 (aliases qsm/ksm, both dead by then)
__global__ __launch_bounds__(256, 1)
void k_attn(const float* __restrict__ x, const float* __restrict__ g1, const float* __restrict__ b1,
            const short* __restrict__ Wqkv, const float* __restrict__ qkvb,
            const short* __restrict__ Wproj, const float* __restrict__ projb,
            const float* __restrict__ battn, float* __restrict__ y) {
    __shared__ __align__(16) char smem[123904];
    short* xln = (short*)smem;
    short* qsm = (short*)(smem + 25600);
    short* ksm = (short*)(smem + 56320);
    short* vsT = (short*)(smem + 87040);
    short* Pb  = (short*)(smem + 114688);
    float* pout = (float*)(smem + 25600);

    const int tid = threadIdx.x;
    const int wv = tid >> 6, l = tid & 63, l15 = l & 15, lg = l >> 4;
    const int wid = blockIdx.x;
    const int b = wid >> 8, win = wid & 255, wi = win >> 4, wj = win & 15;

    // ---- Phase A: LN1 (4 threads per token) ----
    const int t = tid >> 2, sub = tid & 3;
    const int r = t >> 3, c = t & 7;
    const int gi = (wi * 8 + r + 4) & 127, gj = (wj * 8 + c + 4) & 127;
    const size_t rowoff = ((size_t)b * 16384 + (size_t)gi * 128 + gj) * 180 + sub * 45;
    const float* xrow = x + rowoff;
    float xres[45];
    float s1 = 0.f, s2 = 0.f;
#pragma unroll
    for (int j = 0; j < 45; ++j) { float v = xrow[j]; xres[j] = v; s1 += v; s2 += v * v; }
    s1 += __shfl_xor(s1, 1); s2 += __shfl_xor(s2, 1);
    s1 += __shfl_xor(s1, 2); s2 += __shfl_xor(s2, 2);
    const float mu = s1 * (1.f / 180.f);
    const float rstd = rsqrtf(s2 * (1.f / 180.f) - mu * mu + 1e-5f);
#pragma unroll
    for (int j = 0; j < 45; ++j) {
        int ch = sub * 45 + j;
        xln[t * 200 + ch] = f2bf((xres[j] - mu) * rstd * g1[ch] + b1[ch]);
    }
#pragma unroll
    for (int j = 0; j < 5; ++j) xln[t * 200 + 180 + sub * 5 + j] = 0;   // K pad
    for (int idx = tid; idx < 6 * 64; idx += 256) {                     // q/k HD pad (k=30,31)
        qsm[idx * 40 + 30] = 0; qsm[idx * 40 + 31] = 0;
        ksm[idx * 40 + 30] = 0; ksm[idx * 40 + 31] = 0;
    }
    __syncthreads();

    // ---- Phase B: QKV GEMM (64x192 @ 192x544) ----
    s16x8 af[4][6];
#pragma unroll
    for (int i = 0; i < 4; ++i)
#pragma unroll
        for (int ks = 0; ks < 6; ++ks)
            af[i][ks] = *(const s16x8*)&xln[(i * 16 + l15) * 200 + ks * 32 + lg * 8];

    const f32x4 vzero = {0.f, 0.f, 0.f, 0.f};
    for (int j = wv; j < 34; j += 4) {
        f32x4 acc[4];
#pragma unroll
        for (int i = 0; i < 4; ++i) acc[i] = vzero;
#pragma unroll
        for (int ks = 0; ks < 6; ++ks) {
            s16x8 bf = *(const s16x8*)&Wqkv[(j * 16 + l15) * 192 + ks * 32 + lg * 8];
#pragma unroll
            for (int i = 0; i < 4; ++i) acc[i] = mfma16(af[i][ks], bf, acc[i]);
        }
        int cch = j * 16 + l15;
        if (cch < 540) {
            float bias = qkvb[cch];
            int seg = cch / 180;
            int c2 = cch - seg * 180;
            int hh = c2 / 30, hd = c2 - hh * 30;
#pragma unroll
            for (int i = 0; i < 4; ++i)
#pragma unroll
                for (int tt = 0; tt < 4; ++tt) {
                    int row = i * 16 + lg * 4 + tt;
                    float v = acc[i][tt] + bias;
                    if (seg == 0)      qsm[(hh * 64 + row) * 40 + hd] = f2bf(v * 0.18257418583505536f);
                    else if (seg == 1) ksm[(hh * 64 + row) * 40 + hd] = f2bf(v);
                    else               vsT[(hh * 32 + hd) * 72 + row] = f2bf(v);
                }
        }
    }
    __syncthreads();

    // ---- Phase C: attention. wave wv owns row-block i=wv for all 6 heads ----
    const int ib = wv;
    for (int hh = 0; hh < 6; ++hh) {
        s16x8 qf = *(const s16x8*)&qsm[(hh * 64 + ib * 16 + l15) * 40 + lg * 8];
        f32x4 sc[4];
#pragma unroll
        for (int j = 0; j < 4; ++j) {
            s16x8 kf = *(const s16x8*)&ksm[(hh * 64 + j * 16 + l15) * 40 + lg * 8];
            sc[j] = mfma16(qf, kf, vzero);
        }
        const float* bb = battn + hh * 4096;
        float p[4][4];
        const bool edge = (wi == 15) || (wj == 15);
#pragma unroll
        for (int j = 0; j < 4; ++j) {
            int m = j * 16 + l15;
            int rm = m >> 3, cm = m & 7;
            int cnt_m = (wi == 15 ? ((rm >= 4) ? 2 : 1) : 0) * 3 + (wj == 15 ? ((cm >= 4) ? 2 : 1) : 0);
#pragma unroll
            for (int tt = 0; tt < 4; ++tt) {
                int n = ib * 16 + lg * 4 + tt;
                float s = sc[j][tt] + bb[n * 64 + m];
                if (edge) {
                    int rn = n >> 3, cn = n & 7;
                    int cnt_n = (wi == 15 ? ((rn >= 4) ? 2 : 1) : 0) * 3 + (wj == 15 ? ((cn >= 4) ? 2 : 1) : 0);
                    if (cnt_n != cnt_m) s -= 100.f;
                }
                p[j][tt] = s;
            }
        }
        float mx[4], sm[4];
#pragma unroll
        for (int tt = 0; tt < 4; ++tt) {
            float m0 = fmaxf(fmaxf(p[0][tt], p[1][tt]), fmaxf(p[2][tt], p[3][tt]));
            m0 = fmaxf(m0, __shfl_xor(m0, 1));
            m0 = fmaxf(m0, __shfl_xor(m0, 2));
            m0 = fmaxf(m0, __shfl_xor(m0, 4));
            m0 = fmaxf(m0, __shfl_xor(m0, 8));
            mx[tt] = m0;
        }
#pragma unroll
        for (int tt = 0; tt < 4; ++tt) {
            float s0 = 0.f;
#pragma unroll
            for (int j = 0; j < 4; ++j) { float e = __expf(p[j][tt] - mx[tt]); p[j][tt] = e; s0 += e; }
            s0 += __shfl_xor(s0, 1); s0 += __shfl_xor(s0, 2);
            s0 += __shfl_xor(s0, 4); s0 += __shfl_xor(s0, 8);
            sm[tt] = __builtin_amdgcn_rcpf(s0);
        }
        short* Pw = Pb + wv * (16 * 72);
#pragma unroll
        for (int j = 0; j < 4; ++j)
#pragma unroll
            for (int tt = 0; tt < 4; ++tt)
                Pw[(lg * 4 + tt) * 72 + j * 16 + l15] = f2bf(p[j][tt] * sm[tt]);

        f32x4 ov[2]; ov[0] = vzero; ov[1] = vzero;
#pragma unroll
        for (int ksv = 0; ksv < 2; ++ksv) {
            s16x8 pa = *(const s16x8*)&Pw[l15 * 72 + ksv * 32 + lg * 8];
#pragma unroll
            for (int j2 = 0; j2 < 2; ++j2) {
                s16x8 vf = *(const s16x8*)&vsT[(hh * 32 + j2 * 16 + l15) * 72 + ksv * 32 + lg * 8];
                ov[j2] = mfma16(pa, vf, ov[j2]);
            }
        }
#pragma unroll
        for (int j2 = 0; j2 < 2; ++j2) {
            int hd = j2 * 16 + l15;
            if (hd < 30) {
#pragma unroll
                for (int tt = 0; tt < 4; ++tt)
                    xln[(ib * 16 + lg * 4 + tt) * 200 + hh * 30 + hd] = f2bf(ov[j2][tt]);
            }
        }
    }
    __syncthreads();

    // ---- Phase D: proj GEMM (64x192 @ 192x192) ----
    s16x8 af2[4][6];
#pragma unroll
    for (int i = 0; i < 4; ++i)
#pragma unroll
        for (int ks = 0; ks < 6; ++ks)
            af2[i][ks] = *(const s16x8*)&xln[(i * 16 + l15) * 200 + ks * 32 + lg * 8];
#pragma unroll
    for (int jl = 0; jl < 3; ++jl) {
        int j = wv * 3 + jl;
        f32x4 acc[4];
#pragma unroll
        for (int i = 0; i < 4; ++i) acc[i] = vzero;
#pragma unroll
        for (int ks = 0; ks < 6; ++ks) {
            s16x8 bf = *(const s16x8*)&Wproj[(j * 16 + l15) * 192 + ks * 32 + lg * 8];
#pragma unroll
            for (int i = 0; i < 4; ++i) acc[i] = mfma16(af2[i][ks], bf, acc[i]);
        }
        int cch = j * 16 + l15;
        if (cch < 180) {
            float pbv = projb[cch];
#pragma unroll
            for (int i = 0; i < 4; ++i)
#pragma unroll
                for (int tt = 0; tt < 4; ++tt)
                    pout[(i * 16 + lg * 4 + tt) * 184 + cch] = acc[i][tt] + pbv;
        }
    }
    __syncthreads();

    // ---- Phase E: y = x + proj_out ----
    float* yrow = y + rowoff;
#pragma unroll
    for (int j = 0; j < 45; ++j)
        yrow[j] = xres[j] + pout[t * 184 + sub * 45 + j];
}

// ---------------- fused LN2 + MLP kernel (in-place on d_out) ----------------
// LDS: ylds bf16 [64][200] @0 (25600); hid bf16 [64][392] @25600 (50176);
//      mo f32 [64][184] @75776 (47104) -> total 122880
__global__ __launch_bounds__(256, 1)
void k_mlp(const float* __restrict__ g2, const float* __restrict__ b2,
           const short* __restrict__ Wfc1, const float* __restrict__ fb1,
           const short* __restrict__ Wfc2, const float* __restrict__ fb2,
           float* __restrict__ out) {
    __shared__ __align__(16) char smem[122880];
    short* ylds = (short*)smem;
    short* hid  = (short*)(smem + 25600);
    float* mo   = (float*)(smem + 75776);

    const int tid = threadIdx.x;
    const int wv = tid >> 6, l = tid & 63, l15 = l & 15, lg = l >> 4;
    const int t = tid >> 2, sub = tid & 3;
    const size_t rowoff = ((size_t)blockIdx.x * 64 + t) * 180 + sub * 45;
    float* yrow = out + rowoff;
    float yres[45];
    float s1 = 0.f, s2 = 0.f;
#pragma unroll
    for (int j = 0; j < 45; ++j) { float v = yrow[j]; yres[j] = v; s1 += v; s2 += v * v; }
    s1 += __shfl_xor(s1, 1); s2 += __shfl_xor(s2, 1);
    s1 += __shfl_xor(s1, 2); s2 += __shfl_xor(s2, 2);
    const float mu = s1 * (1.f / 180.f);
    const float rstd = rsqrtf(s2 * (1.f / 180.f) - mu * mu + 1e-5f);
#pragma unroll
    for (int j = 0; j < 45; ++j) {
        int ch = sub * 45 + j;
        ylds[t * 200 + ch] = f2bf((yres[j] - mu) * rstd * g2[ch] + b2[ch]);
    }
#pragma unroll
    for (int j = 0; j < 5; ++j) ylds[t * 200 + 180 + sub * 5 + j] = 0;
    for (int idx = tid; idx < 64 * 24; idx += 256) {   // hid K-pad cols 360..383
        int rr = idx / 24, cc = idx - rr * 24;
        hid[rr * 392 + 360 + cc] = 0;
    }
    __syncthreads();

    const f32x4 vzero = {0.f, 0.f, 0.f, 0.f};
    // ---- fc1 (64x192 @ 192x368) + GELU ----
    s16x8 af[4][6];
#pragma unroll
    for (int i = 0; i < 4; ++i)
#pragma unroll
        for (int ks = 0; ks < 6; ++ks)
            af[i][ks] = *(const s16x8*)&ylds[(i * 16 + l15) * 200 + ks * 32 + lg * 8];
    for (int j = wv; j < 23; j += 4) {
        f32x4 acc[4];
#pragma unroll
        for (int i = 0; i < 4; ++i) acc[i] = vzero;
#pragma unroll
        for (int ks = 0; ks < 6; ++ks) {
            s16x8 bf = *(const s16x8*)&Wfc1[(j * 16 + l15) * 192 + ks * 32 + lg * 8];
#pragma unroll
            for (int i = 0; i < 4; ++i) acc[i] = mfma16(af[i][ks], bf, acc[i]);
        }
        int cch = j * 16 + l15;
        if (cch < 360) {
            float bv = fb1[cch];
#pragma unroll
            for (int i = 0; i < 4; ++i)
#pragma unroll
                for (int tt = 0; tt < 4; ++tt) {
                    float v = acc[i][tt] + bv;
                    float gl = 0.5f * v * (1.f + erff(v * 0.70710678118654752f));
                    hid[(i * 16 + lg * 4 + tt) * 392 + cch] = f2bf(gl);
                }
        }
    }
    __syncthreads();

    // ---- fc2 (64x384 @ 384x192), K split in two halves ----
    f32x4 acc3[3][4];
#pragma unroll
    for (int jl = 0; jl < 3; ++jl)
#pragma unroll
        for (int i = 0; i < 4; ++i) acc3[jl][i] = vzero;
#pragma unroll
    for (int kh = 0; kh < 2; ++kh) {
        s16x8 a3[4][6];
#pragma unroll
        for (int i = 0; i < 4; ++i)
#pragma unroll
            for (int ks = 0; ks < 6; ++ks)
                a3[i][ks] = *(const s16x8*)&hid[(i * 16 + l15) * 392 + kh * 192 + ks * 32 + lg * 8];
#pragma unroll
        for (int jl = 0; jl < 3; ++jl) {
            int j = wv * 3 + jl;
#pragma unroll
            for (int ks = 0; ks < 6; ++ks) {
                s16x8 bf = *(const s16x8*)&Wfc2[(j * 16 + l15) * 384 + kh * 192 + ks * 32 + lg * 8];
#pragma unroll
                for (int i = 0; i < 4; ++i) acc3[jl][i] = mfma16(a3[i][ks], bf, acc3[jl][i]);
            }
        }
    }
#pragma unroll
    for (int jl = 0; jl < 3; ++jl) {
        int cch = (wv * 3 + jl) * 16 + l15;
        if (cch < 180) {
            float bv = fb2[cch];
#pragma unroll
            for (int i = 0; i < 4; ++i)
#pragma unroll
                for (int tt = 0; tt < 4; ++tt)
                    mo[(i * 16 + lg * 4 + tt) * 184 + cch] = acc3[jl][i][tt] + bv;
        }
    }
    __syncthreads();

    // ---- out = y + mlp ----
#pragma unroll
    for (int j = 0; j < 45; ++j)
        yrow[j] = yres[j] + mo[t * 184 + sub * 45 + j];
}

extern "C" void kernel_launch(void* const* d_in, const int* in_sizes, int n_in,
                              void* d_out, int out_size, void* d_ws, size_t ws_size,
                              hipStream_t stream) {
    (void)in_sizes; (void)n_in; (void)out_size; (void)ws_size;
    const float* x      = (const float*)d_in[0];
    const float* ln1g   = (const float*)d_in[1];
    const float* ln1b   = (const float*)d_in[2];
    const float* qkv_w  = (const float*)d_in[3];
    const float* qkv_b  = (const float*)d_in[4];
    const float* proj_w = (const float*)d_in[5];
    const float* proj_b = (const float*)d_in[6];
    const float* rpb    = (const float*)d_in[7];
    const float* ln2g   = (const float*)d_in[8];
    const float* ln2b   = (const float*)d_in[9];
    const float* fc1_w  = (const float*)d_in[10];
    const float* fc1_b  = (const float*)d_in[11];
    const float* fc2_w  = (const float*)d_in[12];
    const float* fc2_b  = (const float*)d_in[13];
    float* out = (float*)d_out;

    char* ws = (char*)d_ws;
    short* Wqkv  = (short*)(ws + 0);
    short* Wproj = (short*)(ws + 208896);
    short* Wfc1  = (short*)(ws + 282624);
    short* Wfc2  = (short*)(ws + 423936);
    float* battn = (float*)(ws + 571392);

    k_prep<<<256, 256, 0, stream>>>(qkv_w, proj_w, fc1_w, fc2_w, rpb,
                                    Wqkv, Wproj, Wfc1, Wfc2, battn);
    k_attn<<<4096, 256, 0, stream>>>(x, ln1g, ln1b, Wqkv, qkv_b, Wproj, proj_b, battn, out);
    k_mlp<<<4096, 256, 0, stream>>>(ln2g, ln2b, Wfc1, fc1_b, Wfc2, fc2_b, out);
}

// Round 3
// 886.921 us; speedup vs baseline: 1.0497x; 1.0497x over previous
//
#include <hip/hip_runtime.h>
#include <hip/hip_bf16.h>

// Swin block: C=180, NH=6, HD=30, WS=8, SS=4, N=64, B=16, H=W=128, nW=256.
typedef short s16x8 __attribute__((ext_vector_type(8)));
typedef short s16x4 __attribute__((ext_vector_type(4)));
typedef float f32x4 __attribute__((ext_vector_type(4)));

__device__ __forceinline__ short f2bf(float f) {
    __bf16 h = (__bf16)f;
    return __builtin_bit_cast(short, h);
}
__device__ __forceinline__ f32x4 mfma16(s16x8 a, s16x8 b, f32x4 c) {
    return __builtin_amdgcn_mfma_f32_16x16x32_bf16(a, b, c, 0, 0, 0);
}

#define SCALE_Q 0.18257418583505536f

// ---------------- workspace layout (bytes) ----------------
// Whead bf16 [6][96][192] @ 0       (221184)   rows: 0-31 q, 32-63 k, 64-95 v (hd pad to 32)
// Wproj bf16 [192][192]   @ 221184  (73728)
// Wfc1  bf16 [384][192]   @ 294912  (147456)
// Wfc2  bf16 [192][384]   @ 442368  (147456)
// battn f32  [6][64][64]  @ 589824  (98304)
// bh    f32  [6][96]      @ 688128  (2304)     q-scale baked in
// bfc1  f32  [384]        @ 690432  (1536)     total 691968

__global__ void k_prep(const float* __restrict__ qkv_w, const float* __restrict__ qkv_b,
                       const float* __restrict__ proj_w,
                       const float* __restrict__ fc1_w, const float* __restrict__ fc1_b,
                       const float* __restrict__ fc2_w,
                       const float* __restrict__ rpb,
                       short* __restrict__ Whead, short* __restrict__ Wproj,
                       short* __restrict__ Wfc1, short* __restrict__ Wfc2,
                       float* __restrict__ battn, float* __restrict__ bh,
                       float* __restrict__ bfc1) {
    int gt = blockIdx.x * 256 + threadIdx.x;
    int stride = gridDim.x * 256;
    for (int idx = gt; idx < 6 * 96 * 192; idx += stride) {
        int h = idx / (96 * 192), rem = idx - h * 96 * 192;
        int rr = rem / 192, kk = rem - rr * 192;
        int seg = rr >> 5, hd = rr & 31;
        float val = 0.f;
        if (hd < 30 && kk < 180) {
            int ch = seg * 180 + h * 30 + hd;
            val = qkv_w[ch * 180 + kk];
            if (seg == 0) val *= SCALE_Q;
        }
        Whead[idx] = f2bf(val);
    }
    for (int idx = gt; idx < 6 * 96; idx += stride) {
        int h = idx / 96, rr = idx - h * 96;
        int seg = rr >> 5, hd = rr & 31;
        float val = 0.f;
        if (hd < 30) {
            int ch = seg * 180 + h * 30 + hd;
            val = qkv_b[ch];
            if (seg == 0) val *= SCALE_Q;
        }
        bh[idx] = val;
    }
    for (int idx = gt; idx < 192 * 192; idx += stride) {
        int rr = idx / 192, kk = idx - rr * 192;
        Wproj[idx] = (rr < 180 && kk < 180) ? f2bf(proj_w[rr * 180 + kk]) : (short)0;
    }
    for (int idx = gt; idx < 384 * 192; idx += stride) {
        int rr = idx / 192, kk = idx - rr * 192;
        Wfc1[idx] = (rr < 360 && kk < 180) ? f2bf(fc1_w[rr * 180 + kk]) : (short)0;
    }
    for (int idx = gt; idx < 384; idx += stride)
        bfc1[idx] = (idx < 360) ? fc1_b[idx] : 0.f;
    for (int idx = gt; idx < 192 * 384; idx += stride) {
        int rr = idx / 384, kk = idx - rr * 384;
        Wfc2[idx] = (rr < 180 && kk < 360) ? f2bf(fc2_w[rr * 360 + kk]) : (short)0;
    }
    for (int idx = gt; idx < 6 * 64 * 64; idx += stride) {
        int hh = idx >> 12, n = (idx >> 6) & 63, m = idx & 63;
        int r1 = n >> 3, c1 = n & 7, r2 = m >> 3, c2 = m & 7;
        int ridx = (r1 - r2 + 7) * 15 + (c1 - c2 + 7);
        battn[idx] = rpb[ridx * 6 + hh];
    }
}

// ---------------- fused window-attention kernel ----------------
// LDS (51200 B total -> 3 WG/CU):
//  regionA @0     (25600): xln bf16 [64][200]; after af regs loaded, reused as:
//     Qh [64][40] @0, Kh [64][40] @5120, VhT [32][72] @10240, Pb [4][16][72] @14848
//  xout  @25600   (25600): bf16 [64][200] attention output (proj A input)
//  pout  f32 [64][184] @0 aliases everything after proj A-frags in regs
__global__ __launch_bounds__(256, 3)
void k_attn(const float* __restrict__ x, const float* __restrict__ g1, const float* __restrict__ b1,
            const short* __restrict__ Whead, const float* __restrict__ bh,
            const short* __restrict__ Wproj, const float* __restrict__ projb,
            const float* __restrict__ battn, float* __restrict__ y) {
    __shared__ __align__(16) char smem[51200];
    short* xln  = (short*)smem;
    short* Qh   = (short*)smem;
    short* Kh   = (short*)(smem + 5120);
    short* VhT  = (short*)(smem + 10240);
    short* xout = (short*)(smem + 25600);
    float* pout = (float*)smem;

    const int tid = threadIdx.x;
    const int wv = tid >> 6, l = tid & 63, l15 = l & 15, lg = l >> 4;
    short* Pw = (short*)(smem + 14848) + wv * (16 * 72);
    const int wid = blockIdx.x;
    const int b = wid >> 8, win = wid & 255, wi = win >> 4, wj = win & 15;

    const int t = tid >> 2, sub = tid & 3;
    const int r = t >> 3, c = t & 7;
    const int gi = (wi * 8 + r + 4) & 127, gj = (wj * 8 + c + 4) & 127;
    const size_t rowbase = ((size_t)b * 16384 + (size_t)gi * 128 + gj) * 180;
    const float* xrow = x + rowbase;

    // ---- LN1 (4 threads/token, interleaved float4 loads) ----
    {
        float4 v[12];
        float s1 = 0.f, s2 = 0.f;
#pragma unroll
        for (int m = 0; m < 12; ++m) {
            int jj = sub + 4 * m;
            if (jj < 45) {
                float4 t4 = *(const float4*)&xrow[4 * jj];
                v[m] = t4;
                s1 += t4.x + t4.y + t4.z + t4.w;
                s2 += t4.x * t4.x + t4.y * t4.y + t4.z * t4.z + t4.w * t4.w;
            }
        }
        s1 += __shfl_xor(s1, 1); s2 += __shfl_xor(s2, 1);
        s1 += __shfl_xor(s1, 2); s2 += __shfl_xor(s2, 2);
        const float mu = s1 * (1.f / 180.f);
        const float rstd = rsqrtf(s2 * (1.f / 180.f) - mu * mu + 1e-5f);
#pragma unroll
        for (int m = 0; m < 12; ++m) {
            int jj = sub + 4 * m;
            if (jj < 45) {
                float4 g4 = *(const float4*)&g1[4 * jj];
                float4 b4 = *(const float4*)&b1[4 * jj];
                s16x4 w;
                w[0] = f2bf((v[m].x - mu) * rstd * g4.x + b4.x);
                w[1] = f2bf((v[m].y - mu) * rstd * g4.y + b4.y);
                w[2] = f2bf((v[m].z - mu) * rstd * g4.z + b4.z);
                w[3] = f2bf((v[m].w - mu) * rstd * g4.w + b4.w);
                *(s16x4*)&xln[t * 200 + 4 * jj] = w;
            }
        }
    }
    // zero xln K-pad cols 180..199 (A-frags read cols up to 191!)
    for (int idx = tid; idx < 64 * 20; idx += 256)
        xln[(idx / 20) * 200 + 180 + (idx % 20)] = 0;
    // zero xout pad cols 180..199 (proj K-pad)
    for (int idx = tid; idx < 64 * 20; idx += 256)
        xout[(idx / 20) * 200 + 180 + (idx % 20)] = 0;
    __syncthreads();

    // ---- A-fragments to regs; then regionA is reusable ----
    s16x8 af[4][6];
#pragma unroll
    for (int i = 0; i < 4; ++i)
#pragma unroll
        for (int ks = 0; ks < 6; ++ks)
            af[i][ks] = *(const s16x8*)&xln[(i * 16 + l15) * 200 + ks * 32 + lg * 8];
    __syncthreads();

    const f32x4 vzero = {0.f, 0.f, 0.f, 0.f};
    const bool edge = (wi == 15) || (wj == 15);

    for (int h = 0; h < 6; ++h) {
        const short* Wh = Whead + h * 96 * 192;
        const float* bhh = bh + h * 96;
        const int jA = (3 * wv) >> 1;

#define QKV_TILE(J, IS, IC) do {                                                   \
    f32x4 acc[IC];                                                                 \
    _Pragma("unroll") for (int ii = 0; ii < IC; ++ii) acc[ii] = vzero;             \
    _Pragma("unroll") for (int ks = 0; ks < 6; ++ks) {                             \
        s16x8 bf = *(const s16x8*)&Wh[((J) * 16 + l15) * 192 + ks * 32 + lg * 8];  \
        _Pragma("unroll") for (int ii = 0; ii < IC; ++ii)                          \
            acc[ii] = mfma16(af[(IS) + ii][ks], bf, acc[ii]);                      \
    }                                                                              \
    int rr = (J) * 16 + l15; int seg = (J) >> 1; int hd = rr & 31;                 \
    float bias = bhh[rr];                                                          \
    _Pragma("unroll") for (int ii = 0; ii < IC; ++ii)                              \
    _Pragma("unroll") for (int tt = 0; tt < 4; ++tt) {                             \
        int row = ((IS) + ii) * 16 + lg * 4 + tt;                                  \
        float val = acc[ii][tt] + bias;                                            \
        if (seg == 0)      Qh[row * 40 + hd] = f2bf(val);                          \
        else if (seg == 1) Kh[row * 40 + hd] = f2bf(val);                          \
        else               VhT[hd * 72 + row] = f2bf(val);                         \
    }                                                                              \
} while (0)

        if (!(wv & 1)) { QKV_TILE(jA, 0, 4); QKV_TILE(jA + 1, 0, 2); }
        else           { QKV_TILE(jA, 2, 2); QKV_TILE(jA + 1, 0, 4); }
#undef QKV_TILE
        __syncthreads();

        // ---- attention for head h; wave wv owns q-row block wv ----
        s16x8 qf = *(const s16x8*)&Qh[(wv * 16 + l15) * 40 + lg * 8];
        f32x4 sc[4];
#pragma unroll
        for (int j = 0; j < 4; ++j) {
            s16x8 kf = *(const s16x8*)&Kh[(j * 16 + l15) * 40 + lg * 8];
            sc[j] = mfma16(qf, kf, vzero);
        }
        const float* bb = battn + h * 4096;
        float p[4][4];
#pragma unroll
        for (int j = 0; j < 4; ++j) {
            int m = j * 16 + l15;
            int rm = m >> 3, cm = m & 7;
            int cnt_m = (wi == 15 ? ((rm >= 4) ? 2 : 1) : 0) * 3 + (wj == 15 ? ((cm >= 4) ? 2 : 1) : 0);
#pragma unroll
            for (int tt = 0; tt < 4; ++tt) {
                int n = wv * 16 + lg * 4 + tt;
                float s = sc[j][tt] + bb[n * 64 + m];
                if (edge) {
                    int rn = n >> 3, cn = n & 7;
                    int cnt_n = (wi == 15 ? ((rn >= 4) ? 2 : 1) : 0) * 3 + (wj == 15 ? ((cn >= 4) ? 2 : 1) : 0);
                    if (cnt_n != cnt_m) s -= 100.f;
                }
                p[j][tt] = s;
            }
        }
        float mx[4], sm[4];
#pragma unroll
        for (int tt = 0; tt < 4; ++tt) {
            float m0 = fmaxf(fmaxf(p[0][tt], p[1][tt]), fmaxf(p[2][tt], p[3][tt]));
            m0 = fmaxf(m0, __shfl_xor(m0, 1));
            m0 = fmaxf(m0, __shfl_xor(m0, 2));
            m0 = fmaxf(m0, __shfl_xor(m0, 4));
            m0 = fmaxf(m0, __shfl_xor(m0, 8));
            mx[tt] = m0;
        }
#pragma unroll
        for (int tt = 0; tt < 4; ++tt) {
            float s0 = 0.f;
#pragma unroll
            for (int j = 0; j < 4; ++j) { float e = __expf(p[j][tt] - mx[tt]); p[j][tt] = e; s0 += e; }
            s0 += __shfl_xor(s0, 1); s0 += __shfl_xor(s0, 2);
            s0 += __shfl_xor(s0, 4); s0 += __shfl_xor(s0, 8);
            sm[tt] = __builtin_amdgcn_rcpf(s0);
        }
#pragma unroll
        for (int j = 0; j < 4; ++j)
#pragma unroll
            for (int tt = 0; tt < 4; ++tt)
                Pw[(lg * 4 + tt) * 72 + j * 16 + l15] = f2bf(p[j][tt] * sm[tt]);

        f32x4 ov[2]; ov[0] = vzero; ov[1] = vzero;
#pragma unroll
        for (int ksv = 0; ksv < 2; ++ksv) {
            s16x8 pa = *(const s16x8*)&Pw[l15 * 72 + ksv * 32 + lg * 8];
#pragma unroll
            for (int j2 = 0; j2 < 2; ++j2) {
                s16x8 vf = *(const s16x8*)&VhT[(j2 * 16 + l15) * 72 + ksv * 32 + lg * 8];
                ov[j2] = mfma16(pa, vf, ov[j2]);
            }
        }
#pragma unroll
        for (int j2 = 0; j2 < 2; ++j2) {
            int hd = j2 * 16 + l15;
            if (hd < 30) {
#pragma unroll
                for (int tt = 0; tt < 4; ++tt)
                    xout[(wv * 16 + lg * 4 + tt) * 200 + h * 30 + hd] = f2bf(ov[j2][tt]);
            }
        }
        __syncthreads();
    }

    // ---- proj GEMM: A-frags from xout to regs, then pout aliases LDS ----
    s16x8 af2[4][6];
#pragma unroll
    for (int i = 0; i < 4; ++i)
#pragma unroll
        for (int ks = 0; ks < 6; ++ks)
            af2[i][ks] = *(const s16x8*)&xout[(i * 16 + l15) * 200 + ks * 32 + lg * 8];
    __syncthreads();

#pragma unroll
    for (int jl = 0; jl < 3; ++jl) {
        int j = wv * 3 + jl;
        f32x4 acc[4];
#pragma unroll
        for (int i = 0; i < 4; ++i) acc[i] = vzero;
#pragma unroll
        for (int ks = 0; ks < 6; ++ks) {
            s16x8 bf = *(const s16x8*)&Wproj[(j * 16 + l15) * 192 + ks * 32 + lg * 8];
#pragma unroll
            for (int i = 0; i < 4; ++i) acc[i] = mfma16(af2[i][ks], bf, acc[i]);
        }
        int cch = j * 16 + l15;
        if (cch < 180) {
            float pbv = projb[cch];
#pragma unroll
            for (int i = 0; i < 4; ++i)
#pragma unroll
                for (int tt = 0; tt < 4; ++tt)
                    pout[(i * 16 + lg * 4 + tt) * 184 + cch] = acc[i][tt] + pbv;
        }
    }
    __syncthreads();

    // ---- y = x + proj_out (re-read x, float4 coalesced) ----
    float* yrow = y + rowbase;
#pragma unroll
    for (int m = 0; m < 12; ++m) {
        int jj = sub + 4 * m;
        if (jj < 45) {
            float4 xv = *(const float4*)&xrow[4 * jj];
            float4 pv = *(const float4*)&pout[t * 184 + 4 * jj];
            float4 o;
            o.x = xv.x + pv.x; o.y = xv.y + pv.y; o.z = xv.z + pv.z; o.w = xv.w + pv.w;
            *(float4*)&yrow[4 * jj] = o;
        }
    }
}

// ---------------- fused LN2 + MLP kernel (in-place on d_out) ----------------
// LDS (51200 B -> 3 WG/CU): ylds bf16 [64][200] @0; hid bf16 [64][200] @25600
// (192 cols used per K-half); mo f32 [64][184] @0 aliases after fc2 done.
__global__ __launch_bounds__(256, 3)
void k_mlp(const float* __restrict__ g2, const float* __restrict__ b2,
           const short* __restrict__ Wfc1, const float* __restrict__ bfc1,
           const short* __restrict__ Wfc2, const float* __restrict__ fb2,
           float* __restrict__ out) {
    __shared__ __align__(16) char smem[51200];
    short* ylds = (short*)smem;
    short* hid  = (short*)(smem + 25600);
    float* mo   = (float*)smem;

    const int tid = threadIdx.x;
    const int wv = tid >> 6, l = tid & 63, l15 = l & 15, lg = l >> 4;
    const int t = tid >> 2, sub = tid & 3;
    const size_t rowbase = ((size_t)blockIdx.x * 64 + t) * 180;
    float* yrow = out + rowbase;

    // ---- LN2 ----
    {
        float4 v[12];
        float s1 = 0.f, s2 = 0.f;
#pragma unroll
        for (int m = 0; m < 12; ++m) {
            int jj = sub + 4 * m;
            if (jj < 45) {
                float4 t4 = *(const float4*)&yrow[4 * jj];
                v[m] = t4;
                s1 += t4.x + t4.y + t4.z + t4.w;
                s2 += t4.x * t4.x + t4.y * t4.y + t4.z * t4.z + t4.w * t4.w;
            }
        }
        s1 += __shfl_xor(s1, 1); s2 += __shfl_xor(s2, 1);
        s1 += __shfl_xor(s1, 2); s2 += __shfl_xor(s2, 2);
        const float mu = s1 * (1.f / 180.f);
        const float rstd = rsqrtf(s2 * (1.f / 180.f) - mu * mu + 1e-5f);
#pragma unroll
        for (int m = 0; m < 12; ++m) {
            int jj = sub + 4 * m;
            if (jj < 45) {
                float4 g4 = *(const float4*)&g2[4 * jj];
                float4 b4 = *(const float4*)&b2[4 * jj];
                s16x4 w;
                w[0] = f2bf((v[m].x - mu) * rstd * g4.x + b4.x);
                w[1] = f2bf((v[m].y - mu) * rstd * g4.y + b4.y);
                w[2] = f2bf((v[m].z - mu) * rstd * g4.z + b4.z);
                w[3] = f2bf((v[m].w - mu) * rstd * g4.w + b4.w);
                *(s16x4*)&ylds[t * 200 + 4 * jj] = w;
            }
        }
    }
    for (int idx = tid; idx < 64 * 20; idx += 256)
        ylds[(idx / 20) * 200 + 180 + (idx % 20)] = 0;
    __syncthreads();

    const f32x4 vzero = {0.f, 0.f, 0.f, 0.f};
    f32x4 acc3[3][4];
#pragma unroll
    for (int jl = 0; jl < 3; ++jl)
#pragma unroll
        for (int i = 0; i < 4; ++i) acc3[jl][i] = vzero;

    for (int kh = 0; kh < 2; ++kh) {
        // ---- fc1 half: out channels [kh*192, kh*192+192) ----
        f32x4 accf[3][4];
#pragma unroll
        for (int jl = 0; jl < 3; ++jl)
#pragma unroll
            for (int i = 0; i < 4; ++i) accf[jl][i] = vzero;
#pragma unroll
        for (int ks = 0; ks < 6; ++ks) {
            s16x8 a[4];
#pragma unroll
            for (int i = 0; i < 4; ++i)
                a[i] = *(const s16x8*)&ylds[(i * 16 + l15) * 200 + ks * 32 + lg * 8];
#pragma unroll
            for (int jl = 0; jl < 3; ++jl) {
                int jrow = (kh * 12 + wv * 3 + jl) * 16 + l15;
                s16x8 bf = *(const s16x8*)&Wfc1[jrow * 192 + ks * 32 + lg * 8];
#pragma unroll
                for (int i = 0; i < 4; ++i) accf[jl][i] = mfma16(a[i], bf, accf[jl][i]);
            }
        }
#pragma unroll
        for (int jl = 0; jl < 3; ++jl) {
            int cl = (wv * 3 + jl) * 16 + l15;         // 0..191 within half
            float bv = bfc1[kh * 192 + cl];
#pragma unroll
            for (int i = 0; i < 4; ++i)
#pragma unroll
                for (int tt = 0; tt < 4; ++tt) {
                    float vv = accf[jl][i][tt] + bv;
                    float gl = 0.5f * vv * (1.f + erff(vv * 0.7071067811865476f));
                    hid[(i * 16 + lg * 4 + tt) * 200 + cl] = f2bf(gl);
                }
        }
        __syncthreads();

        // ---- fc2 partial over this K-half ----
#pragma unroll
        for (int ks = 0; ks < 6; ++ks) {
            s16x8 a[4];
#pragma unroll
            for (int i = 0; i < 4; ++i)
                a[i] = *(const s16x8*)&hid[(i * 16 + l15) * 200 + ks * 32 + lg * 8];
#pragma unroll
            for (int jl = 0; jl < 3; ++jl) {
                s16x8 bf = *(const s16x8*)&Wfc2[((wv * 3 + jl) * 16 + l15) * 384 + kh * 192 + ks * 32 + lg * 8];
#pragma unroll
                for (int i = 0; i < 4; ++i) acc3[jl][i] = mfma16(a[i], bf, acc3[jl][i]);
            }
        }
        __syncthreads();
    }

    // ---- mo = fc2 + bias (aliases ylds/hid, all reads done) ----
#pragma unroll
    for (int jl = 0; jl < 3; ++jl) {
        int cch = (wv * 3 + jl) * 16 + l15;
        if (cch < 180) {
            float bv = fb2[cch];
#pragma unroll
            for (int i = 0; i < 4; ++i)
#pragma unroll
                for (int tt = 0; tt < 4; ++tt)
                    mo[(i * 16 + lg * 4 + tt) * 184 + cch] = acc3[jl][i][tt] + bv;
        }
    }
    __syncthreads();

    // ---- out = y + mlp ----
#pragma unroll
    for (int m = 0; m < 12; ++m) {
        int jj = sub + 4 * m;
        if (jj < 45) {
            float4 yv = *(const float4*)&yrow[4 * jj];
            float4 mv = *(const float4*)&mo[t * 184 + 4 * jj];
            float4 o;
            o.x = yv.x + mv.x; o.y = yv.y + mv.y; o.z = yv.z + mv.z; o.w = yv.w + mv.w;
            *(float4*)&yrow[4 * jj] = o;
        }
    }
}

extern "C" void kernel_launch(void* const* d_in, const int* in_sizes, int n_in,
                              void* d_out, int out_size, void* d_ws, size_t ws_size,
                              hipStream_t stream) {
    (void)in_sizes; (void)n_in; (void)out_size; (void)ws_size;
    const float* x      = (const float*)d_in[0];
    const float* ln1g   = (const float*)d_in[1];
    const float* ln1b   = (const float*)d_in[2];
    const float* qkv_w  = (const float*)d_in[3];
    const float* qkv_b  = (const float*)d_in[4];
    const float* proj_w = (const float*)d_in[5];
    const float* proj_b = (const float*)d_in[6];
    const float* rpb    = (const float*)d_in[7];
    const float* ln2g   = (const float*)d_in[8];
    const float* ln2b   = (const float*)d_in[9];
    const float* fc1_w  = (const float*)d_in[10];
    const float* fc1_b  = (const float*)d_in[11];
    const float* fc2_w  = (const float*)d_in[12];
    const float* fc2_b  = (const float*)d_in[13];
    float* out = (float*)d_out;

    char* ws = (char*)d_ws;
    short* Whead = (short*)(ws + 0);
    short* Wproj = (short*)(ws + 221184);
    short* Wfc1  = (short*)(ws + 294912);
    short* Wfc2  = (short*)(ws + 442368);
    float* battn = (float*)(ws + 589824);
    float* bh    = (float*)(ws + 688128);
    float* bfc1p = (float*)(ws + 690432);

    k_prep<<<256, 256, 0, stream>>>(qkv_w, qkv_b, proj_w, fc1_w, fc1_b, fc2_w, rpb,
                                    Whead, Wproj, Wfc1, Wfc2, battn, bh, bfc1p);
    k_attn<<<4096, 256, 0, stream>>>(x, ln1g, ln1b, Whead, bh, Wproj, proj_b, battn, out);
    k_mlp<<<4096, 256, 0, stream>>>(ln2g, ln2b, Wfc1, bfc1p, Wfc2, fc2_b, out);
}

// Round 4
// 703.420 us; speedup vs baseline: 1.3235x; 1.2609x over previous
//
#include <hip/hip_runtime.h>
#include <hip/hip_bf16.h>

// Swin block fused: C=180, NH=6, HD=30, WS=8, SS=4, N=64, B=16, H=W=128.
typedef short s16x8 __attribute__((ext_vector_type(8)));
typedef short s16x4 __attribute__((ext_vector_type(4)));
typedef float f32x4 __attribute__((ext_vector_type(4)));

__device__ __forceinline__ short f2bf(float f) {
    __bf16 h = (__bf16)f;
    return __builtin_bit_cast(short, h);
}
__device__ __forceinline__ f32x4 mfma16(s16x8 a, s16x8 b, f32x4 c) {
    return __builtin_amdgcn_mfma_f32_16x16x32_bf16(a, b, c, 0, 0, 0);
}
// Wait for all our DS ops to land; memory clobber stops compiler moving mem ops across.
#define LDS_FENCE() asm volatile("s_waitcnt lgkmcnt(0)" ::: "memory")

#define SCALE_Q 0.18257418583505536f

// ---------------- workspace layout (bytes) ----------------
// Whead bf16 [6][96][192] @ 0       rows: 0-31 q(scaled), 32-63 k, 64-95 v (hd pad 32)
// Wproj bf16 [192][192]   @ 221184
// Wfc1  bf16 [384][192]   @ 294912
// Wfc2  bf16 [192][384]   @ 442368
// battn f32  [6][64][64]  @ 589824
// bh    f32  [6][96]      @ 688128
// bfc1  f32  [384]        @ 690432   total 691968

__global__ void k_prep(const float* __restrict__ qkv_w, const float* __restrict__ qkv_b,
                       const float* __restrict__ proj_w,
                       const float* __restrict__ fc1_w, const float* __restrict__ fc1_b,
                       const float* __restrict__ fc2_w,
                       const float* __restrict__ rpb,
                       short* __restrict__ Whead, short* __restrict__ Wproj,
                       short* __restrict__ Wfc1, short* __restrict__ Wfc2,
                       float* __restrict__ battn, float* __restrict__ bh,
                       float* __restrict__ bfc1) {
    int gt = blockIdx.x * 256 + threadIdx.x;
    int stride = gridDim.x * 256;
    for (int idx = gt; idx < 6 * 96 * 192; idx += stride) {
        int h = idx / (96 * 192), rem = idx - h * 96 * 192;
        int rr = rem / 192, kk = rem - rr * 192;
        int seg = rr >> 5, hd = rr & 31;
        float val = 0.f;
        if (hd < 30 && kk < 180) {
            int ch = seg * 180 + h * 30 + hd;
            val = qkv_w[ch * 180 + kk];
            if (seg == 0) val *= SCALE_Q;
        }
        Whead[idx] = f2bf(val);
    }
    for (int idx = gt; idx < 6 * 96; idx += stride) {
        int h = idx / 96, rr = idx - h * 96;
        int seg = rr >> 5, hd = rr & 31;
        float val = 0.f;
        if (hd < 30) {
            int ch = seg * 180 + h * 30 + hd;
            val = qkv_b[ch];
            if (seg == 0) val *= SCALE_Q;
        }
        bh[idx] = val;
    }
    for (int idx = gt; idx < 192 * 192; idx += stride) {
        int rr = idx / 192, kk = idx - rr * 192;
        Wproj[idx] = (rr < 180 && kk < 180) ? f2bf(proj_w[rr * 180 + kk]) : (short)0;
    }
    for (int idx = gt; idx < 384 * 192; idx += stride) {
        int rr = idx / 192, kk = idx - rr * 192;
        Wfc1[idx] = (rr < 360 && kk < 180) ? f2bf(fc1_w[rr * 180 + kk]) : (short)0;
    }
    for (int idx = gt; idx < 384; idx += stride)
        bfc1[idx] = (idx < 360) ? fc1_b[idx] : 0.f;
    for (int idx = gt; idx < 192 * 384; idx += stride) {
        int rr = idx / 384, kk = idx - rr * 384;
        Wfc2[idx] = (rr < 180 && kk < 360) ? f2bf(fc2_w[rr * 360 + kk]) : (short)0;
    }
    for (int idx = gt; idx < 6 * 64 * 64; idx += stride) {
        int hh = idx >> 12, n = (idx >> 6) & 63, m = idx & 63;
        int r1 = n >> 3, c1 = n & 7, r2 = m >> 3, c2 = m & 7;
        int ridx = (r1 - r2 + 7) * 15 + (c1 - c2 + 7);
        battn[idx] = rpb[ridx * 6 + hh];
    }
}

// ---------------- fully fused kernel ----------------
// One block per window, 384 threads = 6 waves; wave h owns head h end-to-end.
// LDS (80896 B -> 2 WG/CU):
//   patches: 6 x 9216 @ 0        wave-private Q/K/V/P transpose scratch
//            (initially aliased by xln bf16 [64][200] @ 0)
//   xout bf16 [64][200] @ 55296  (later ylds for LN2 output)
//   pout f32  [64][184] @ 0      (proj out; later mo = fc2 out) spans patches
//   hid  bf16 [64][200] @ 0      (fc1 out, per K-half)
__global__ __launch_bounds__(384, 3)
void k_fused(const float* __restrict__ x, const float* __restrict__ g1, const float* __restrict__ b1,
             const short* __restrict__ Whead, const float* __restrict__ bh,
             const short* __restrict__ Wproj, const float* __restrict__ projb,
             const float* __restrict__ battn,
             const float* __restrict__ g2, const float* __restrict__ b2,
             const short* __restrict__ Wfc1, const float* __restrict__ bfc1,
             const short* __restrict__ Wfc2, const float* __restrict__ fb2,
             float* __restrict__ out) {
    __shared__ __align__(16) char smem[80896];
    short* xln  = (short*)smem;                 // [64][200]
    short* xout = (short*)(smem + 55296);       // [64][200]; later ylds
    float* pout = (float*)smem;                 // [64][184] f32; later mo
    short* hid  = (short*)smem;                 // [64][200]

    const int tid = threadIdx.x;
    const int wv = tid >> 6, l = tid & 63, l15 = l & 15, lg = l >> 4;
    const int wid = blockIdx.x;
    const int b = wid >> 8, win = wid & 255, wi = win >> 4, wj = win & 15;
    const bool edge = (wi == 15) || (wj == 15);
    const f32x4 vzero = {0.f, 0.f, 0.f, 0.f};

    // per-token addressing for the 4-threads-per-token phases (tid < 256 only)
    const int t = tid >> 2, sub = tid & 3;
    size_t rowbase = 0;
    if (tid < 256) {
        const int r = t >> 3, c = t & 7;
        const int gi = (wi * 8 + r + 4) & 127, gj = (wj * 8 + c + 4) & 127;
        rowbase = ((size_t)b * 16384 + (size_t)gi * 128 + gj) * 180;
    }
    const float* xrow = x + rowbase;

    // ---- Phase 1: LN1 (waves 0-3); waves 4-5 zero the K-pads ----
    if (tid < 256) {
        float4 v[12];
        float s1 = 0.f, s2 = 0.f;
#pragma unroll
        for (int m = 0; m < 12; ++m) {
            int jj = sub + 4 * m;
            if (jj < 45) {
                float4 t4 = *(const float4*)&xrow[4 * jj];
                v[m] = t4;
                s1 += t4.x + t4.y + t4.z + t4.w;
                s2 += t4.x * t4.x + t4.y * t4.y + t4.z * t4.z + t4.w * t4.w;
            }
        }
        s1 += __shfl_xor(s1, 1); s2 += __shfl_xor(s2, 1);
        s1 += __shfl_xor(s1, 2); s2 += __shfl_xor(s2, 2);
        const float mu = s1 * (1.f / 180.f);
        const float rstd = rsqrtf(s2 * (1.f / 180.f) - mu * mu + 1e-5f);
#pragma unroll
        for (int m = 0; m < 12; ++m) {
            int jj = sub + 4 * m;
            if (jj < 45) {
                float4 g4 = *(const float4*)&g1[4 * jj];
                float4 b4 = *(const float4*)&b1[4 * jj];
                s16x4 w;
                w[0] = f2bf((v[m].x - mu) * rstd * g4.x + b4.x);
                w[1] = f2bf((v[m].y - mu) * rstd * g4.y + b4.y);
                w[2] = f2bf((v[m].z - mu) * rstd * g4.z + b4.z);
                w[3] = f2bf((v[m].w - mu) * rstd * g4.w + b4.w);
                *(s16x4*)&xln[t * 200 + 4 * jj] = w;
            }
        }
    } else {
        for (int k = tid - 256; k < 64 * 20; k += 128) {
            int rr = k / 20, cc = k - rr * 20;
            xln[rr * 200 + 180 + cc] = 0;
            xout[rr * 200 + 180 + cc] = 0;
        }
    }
    __syncthreads();   // B1: xln ready

    // ---- A-fragments (all 64 tokens x K=192) into regs ----
    s16x8 af[4][6];
#pragma unroll
    for (int i = 0; i < 4; ++i)
#pragma unroll
        for (int ks = 0; ks < 6; ++ks)
            af[i][ks] = *(const s16x8*)&xln[(i * 16 + l15) * 200 + ks * 32 + lg * 8];
    __syncthreads();   // B2: xln dead -> patches usable

    // ---- Phase 2: per-wave head pipeline (no barriers inside) ----
    {
        short* patch = (short*)(smem + wv * 9216);
        const short* Wh = Whead + wv * (96 * 192);
        const float* bhh = bh + wv * 96;
        const float* bb = battn + wv * 4096;

        // Q tiles (rows 0..31 of Wh), store [64][40]
#pragma unroll
        for (int j = 0; j < 2; ++j) {
            f32x4 acc[4] = {vzero, vzero, vzero, vzero};
#pragma unroll
            for (int ks = 0; ks < 6; ++ks) {
                s16x8 bf = *(const s16x8*)&Wh[(j * 16 + l15) * 192 + ks * 32 + lg * 8];
#pragma unroll
                for (int i = 0; i < 4; ++i) acc[i] = mfma16(af[i][ks], bf, acc[i]);
            }
            float bias = bhh[j * 16 + l15];
            int hd = j * 16 + l15;
#pragma unroll
            for (int i = 0; i < 4; ++i)
#pragma unroll
                for (int tt = 0; tt < 4; ++tt)
                    patch[(i * 16 + lg * 4 + tt) * 40 + hd] = f2bf(acc[i][tt] + bias);
        }
        LDS_FENCE();
        s16x8 qf[4];
#pragma unroll
        for (int i = 0; i < 4; ++i) qf[i] = *(const s16x8*)&patch[(i * 16 + l15) * 40 + lg * 8];
        LDS_FENCE();

        // K tiles (rows 32..63), store [64][36]
#pragma unroll
        for (int j = 2; j < 4; ++j) {
            f32x4 acc[4] = {vzero, vzero, vzero, vzero};
#pragma unroll
            for (int ks = 0; ks < 6; ++ks) {
                s16x8 bf = *(const s16x8*)&Wh[(j * 16 + l15) * 192 + ks * 32 + lg * 8];
#pragma unroll
                for (int i = 0; i < 4; ++i) acc[i] = mfma16(af[i][ks], bf, acc[i]);
            }
            float bias = bhh[j * 16 + l15];
            int hd = (j - 2) * 16 + l15;
#pragma unroll
            for (int i = 0; i < 4; ++i)
#pragma unroll
                for (int tt = 0; tt < 4; ++tt)
                    patch[(i * 16 + lg * 4 + tt) * 36 + hd] = f2bf(acc[i][tt] + bias);
        }
        LDS_FENCE();
        s16x8 kf[4];
#pragma unroll
        for (int jj = 0; jj < 4; ++jj) kf[jj] = *(const s16x8*)&patch[(jj * 16 + l15) * 36 + lg * 8];
        LDS_FENCE();

        // V tiles (rows 64..95), store transposed VhT [32][72]
#pragma unroll
        for (int j = 4; j < 6; ++j) {
            f32x4 acc[4] = {vzero, vzero, vzero, vzero};
#pragma unroll
            for (int ks = 0; ks < 6; ++ks) {
                s16x8 bf = *(const s16x8*)&Wh[(j * 16 + l15) * 192 + ks * 32 + lg * 8];
#pragma unroll
                for (int i = 0; i < 4; ++i) acc[i] = mfma16(af[i][ks], bf, acc[i]);
            }
            float bias = bhh[j * 16 + l15];
            int hd = (j - 4) * 16 + l15;
#pragma unroll
            for (int i = 0; i < 4; ++i)
#pragma unroll
                for (int tt = 0; tt < 4; ++tt)
                    patch[hd * 72 + i * 16 + lg * 4 + tt] = f2bf(acc[i][tt] + bias);
        }
        LDS_FENCE();
        s16x8 vf[2][2];
#pragma unroll
        for (int j2 = 0; j2 < 2; ++j2)
#pragma unroll
            for (int ksv = 0; ksv < 2; ++ksv)
                vf[j2][ksv] = *(const s16x8*)&patch[(j2 * 16 + l15) * 72 + ksv * 32 + lg * 8];
        LDS_FENCE();

        // scores + softmax + PV, per q-row-tile i; P tile [16][72] reuses patch
        f32x4 ov[4][2];
#pragma unroll
        for (int i = 0; i < 4; ++i) { ov[i][0] = vzero; ov[i][1] = vzero; }
#pragma unroll
        for (int i = 0; i < 4; ++i) {
            f32x4 sc[4];
#pragma unroll
            for (int j = 0; j < 4; ++j) sc[j] = mfma16(qf[i], kf[j], vzero);
            float p[4][4];
#pragma unroll
            for (int j = 0; j < 4; ++j) {
                int m = j * 16 + l15;
                int rm = m >> 3, cm = m & 7;
                int cnt_m = (wi == 15 ? ((rm >= 4) ? 2 : 1) : 0) * 3 + (wj == 15 ? ((cm >= 4) ? 2 : 1) : 0);
#pragma unroll
                for (int tt = 0; tt < 4; ++tt) {
                    int n = i * 16 + lg * 4 + tt;
                    float s = sc[j][tt] + bb[n * 64 + m];
                    if (edge) {
                        int rn = n >> 3, cn = n & 7;
                        int cnt_n = (wi == 15 ? ((rn >= 4) ? 2 : 1) : 0) * 3 + (wj == 15 ? ((cn >= 4) ? 2 : 1) : 0);
                        if (cnt_n != cnt_m) s -= 100.f;
                    }
                    p[j][tt] = s;
                }
            }
            float mx[4], sm[4];
#pragma unroll
            for (int tt = 0; tt < 4; ++tt) {
                float m0 = fmaxf(fmaxf(p[0][tt], p[1][tt]), fmaxf(p[2][tt], p[3][tt]));
                m0 = fmaxf(m0, __shfl_xor(m0, 1));
                m0 = fmaxf(m0, __shfl_xor(m0, 2));
                m0 = fmaxf(m0, __shfl_xor(m0, 4));
                m0 = fmaxf(m0, __shfl_xor(m0, 8));
                mx[tt] = m0;
            }
#pragma unroll
            for (int tt = 0; tt < 4; ++tt) {
                float s0 = 0.f;
#pragma unroll
                for (int j = 0; j < 4; ++j) { float e = __expf(p[j][tt] - mx[tt]); p[j][tt] = e; s0 += e; }
                s0 += __shfl_xor(s0, 1); s0 += __shfl_xor(s0, 2);
                s0 += __shfl_xor(s0, 4); s0 += __shfl_xor(s0, 8);
                sm[tt] = __builtin_amdgcn_rcpf(s0);
            }
#pragma unroll
            for (int j = 0; j < 4; ++j)
#pragma unroll
                for (int tt = 0; tt < 4; ++tt)
                    patch[(lg * 4 + tt) * 72 + j * 16 + l15] = f2bf(p[j][tt] * sm[tt]);
            LDS_FENCE();
            s16x8 pa0 = *(const s16x8*)&patch[l15 * 72 + lg * 8];
            s16x8 pa1 = *(const s16x8*)&patch[l15 * 72 + 32 + lg * 8];
            LDS_FENCE();   // pa landed before next i overwrites P
            ov[i][0] = mfma16(pa0, vf[0][0], ov[i][0]);
            ov[i][0] = mfma16(pa1, vf[0][1], ov[i][0]);
            ov[i][1] = mfma16(pa0, vf[1][0], ov[i][1]);
            ov[i][1] = mfma16(pa1, vf[1][1], ov[i][1]);
        }
        // attention out -> xout cols [wv*30, wv*30+30)
#pragma unroll
        for (int i = 0; i < 4; ++i)
#pragma unroll
            for (int j2 = 0; j2 < 2; ++j2) {
                int hd = j2 * 16 + l15;
                if (hd < 30) {
#pragma unroll
                    for (int tt = 0; tt < 4; ++tt)
                        xout[(i * 16 + lg * 4 + tt) * 200 + wv * 30 + hd] = f2bf(ov[i][j2][tt]);
                }
            }
    }
    __syncthreads();   // B3: xout complete

    // ---- Phase 3: proj GEMM (N=192 -> 2 tiles/wave), pout f32 spans patches ----
    {
        s16x8 af2[4][6];
#pragma unroll
        for (int i = 0; i < 4; ++i)
#pragma unroll
            for (int ks = 0; ks < 6; ++ks)
                af2[i][ks] = *(const s16x8*)&xout[(i * 16 + l15) * 200 + ks * 32 + lg * 8];
#pragma unroll
        for (int jl = 0; jl < 2; ++jl) {
            int j = wv * 2 + jl;
            f32x4 acc[4] = {vzero, vzero, vzero, vzero};
#pragma unroll
            for (int ks = 0; ks < 6; ++ks) {
                s16x8 bf = *(const s16x8*)&Wproj[(j * 16 + l15) * 192 + ks * 32 + lg * 8];
#pragma unroll
                for (int i = 0; i < 4; ++i) acc[i] = mfma16(af2[i][ks], bf, acc[i]);
            }
            int cch = j * 16 + l15;
            if (cch < 180) {
                float pbv = projb[cch];
#pragma unroll
                for (int i = 0; i < 4; ++i)
#pragma unroll
                    for (int tt = 0; tt < 4; ++tt)
                        pout[(i * 16 + lg * 4 + tt) * 184 + cch] = acc[i][tt] + pbv;
            }
        }
    }
    __syncthreads();   // B4: pout ready

    // ---- Phase 4: y = x + proj (kept in regs), LN2 -> ylds (= xout region) ----
    float4 yv[12];
    short* ylds = xout;   // pads 180..199 still zero
    if (tid < 256) {
        float s1 = 0.f, s2 = 0.f;
#pragma unroll
        for (int m = 0; m < 12; ++m) {
            int jj = sub + 4 * m;
            if (jj < 45) {
                float4 xv = *(const float4*)&xrow[4 * jj];
                float4 pv = *(const float4*)&pout[t * 184 + 4 * jj];
                float4 y4;
                y4.x = xv.x + pv.x; y4.y = xv.y + pv.y; y4.z = xv.z + pv.z; y4.w = xv.w + pv.w;
                yv[m] = y4;
                s1 += y4.x + y4.y + y4.z + y4.w;
                s2 += y4.x * y4.x + y4.y * y4.y + y4.z * y4.z + y4.w * y4.w;
            }
        }
        s1 += __shfl_xor(s1, 1); s2 += __shfl_xor(s2, 1);
        s1 += __shfl_xor(s1, 2); s2 += __shfl_xor(s2, 2);
        const float mu = s1 * (1.f / 180.f);
        const float rstd = rsqrtf(s2 * (1.f / 180.f) - mu * mu + 1e-5f);
#pragma unroll
        for (int m = 0; m < 12; ++m) {
            int jj = sub + 4 * m;
            if (jj < 45) {
                float4 g4 = *(const float4*)&g2[4 * jj];
                float4 b4 = *(const float4*)&b2[4 * jj];
                s16x4 w;
                w[0] = f2bf((yv[m].x - mu) * rstd * g4.x + b4.x);
                w[1] = f2bf((yv[m].y - mu) * rstd * g4.y + b4.y);
                w[2] = f2bf((yv[m].z - mu) * rstd * g4.z + b4.z);
                w[3] = f2bf((yv[m].w - mu) * rstd * g4.w + b4.w);
                *(s16x4*)&ylds[t * 200 + 4 * jj] = w;
            }
        }
    }
    __syncthreads();   // B5: ylds ready, pout dead

    // ---- Phase 5: MLP. fc1: 24 tiles = 2/wave/half; fc2: 12 tiles = 2/wave ----
    f32x4 acc3[2][4];
#pragma unroll
    for (int jl = 0; jl < 2; ++jl)
#pragma unroll
        for (int i = 0; i < 4; ++i) acc3[jl][i] = vzero;

#pragma unroll
    for (int kh = 0; kh < 2; ++kh) {
        f32x4 accf[2][4];
#pragma unroll
        for (int jl = 0; jl < 2; ++jl)
#pragma unroll
            for (int i = 0; i < 4; ++i) accf[jl][i] = vzero;
#pragma unroll
        for (int ks = 0; ks < 6; ++ks) {
            s16x8 a[4];
#pragma unroll
            for (int i = 0; i < 4; ++i)
                a[i] = *(const s16x8*)&ylds[(i * 16 + l15) * 200 + ks * 32 + lg * 8];
#pragma unroll
            for (int jl = 0; jl < 2; ++jl) {
                int jT = kh * 12 + wv * 2 + jl;
                s16x8 bf = *(const s16x8*)&Wfc1[(jT * 16 + l15) * 192 + ks * 32 + lg * 8];
#pragma unroll
                for (int i = 0; i < 4; ++i) accf[jl][i] = mfma16(a[i], bf, accf[jl][i]);
            }
        }
#pragma unroll
        for (int jl = 0; jl < 2; ++jl) {
            int cl = (wv * 2 + jl) * 16 + l15;          // 0..191 within half
            float bv = bfc1[kh * 192 + cl];
#pragma unroll
            for (int i = 0; i < 4; ++i)
#pragma unroll
                for (int tt = 0; tt < 4; ++tt) {
                    float vvv = accf[jl][i][tt] + bv;
                    float gl = 0.5f * vvv * (1.f + erff(vvv * 0.7071067811865476f));
                    hid[(i * 16 + lg * 4 + tt) * 200 + cl] = f2bf(gl);
                }
        }
        __syncthreads();   // hid(kh) ready
#pragma unroll
        for (int ks = 0; ks < 6; ++ks) {
            s16x8 a[4];
#pragma unroll
            for (int i = 0; i < 4; ++i)
                a[i] = *(const s16x8*)&hid[(i * 16 + l15) * 200 + ks * 32 + lg * 8];
#pragma unroll
            for (int jl = 0; jl < 2; ++jl) {
                s16x8 bf = *(const s16x8*)&Wfc2[((wv * 2 + jl) * 16 + l15) * 384 + kh * 192 + ks * 32 + lg * 8];
#pragma unroll
                for (int i = 0; i < 4; ++i) acc3[jl][i] = mfma16(a[i], bf, acc3[jl][i]);
            }
        }
        __syncthreads();   // hid consumed
    }

    // ---- fc2 out + bias -> mo (= pout region) ----
#pragma unroll
    for (int jl = 0; jl < 2; ++jl) {
        int cch = (wv * 2 + jl) * 16 + l15;
        if (cch < 180) {
            float bv = fb2[cch];
#pragma unroll
            for (int i = 0; i < 4; ++i)
#pragma unroll
                for (int tt = 0; tt < 4; ++tt)
                    pout[(i * 16 + lg * 4 + tt) * 184 + cch] = acc3[jl][i][tt] + bv;
        }
    }
    __syncthreads();   // mo ready

    // ---- final: out = y + mlp ----
    if (tid < 256) {
        float* orow = out + rowbase;
#pragma unroll
        for (int m = 0; m < 12; ++m) {
            int jj = sub + 4 * m;
            if (jj < 45) {
                float4 mv = *(const float4*)&pout[t * 184 + 4 * jj];
                float4 o;
                o.x = yv[m].x + mv.x; o.y = yv[m].y + mv.y;
                o.z = yv[m].z + mv.z; o.w = yv[m].w + mv.w;
                *(float4*)&orow[4 * jj] = o;
            }
        }
    }
}

extern "C" void kernel_launch(void* const* d_in, const int* in_sizes, int n_in,
                              void* d_out, int out_size, void* d_ws, size_t ws_size,
                              hipStream_t stream) {
    (void)in_sizes; (void)n_in; (void)out_size; (void)ws_size;
    const float* x      = (const float*)d_in[0];
    const float* ln1g   = (const float*)d_in[1];
    const float* ln1b   = (const float*)d_in[2];
    const float* qkv_w  = (const float*)d_in[3];
    const float* qkv_b  = (const float*)d_in[4];
    const float* proj_w = (const float*)d_in[5];
    const float* proj_b = (const float*)d_in[6];
    const float* rpb    = (const float*)d_in[7];
    const float* ln2g   = (const float*)d_in[8];
    const float* ln2b   = (const float*)d_in[9];
    const float* fc1_w  = (const float*)d_in[10];
    const float* fc1_b  = (const float*)d_in[11];
    const float* fc2_w  = (const float*)d_in[12];
    const float* fc2_b  = (const float*)d_in[13];
    float* out = (float*)d_out;

    char* ws = (char*)d_ws;
    short* Whead = (short*)(ws + 0);
    short* Wproj = (short*)(ws + 221184);
    short* Wfc1  = (short*)(ws + 294912);
    short* Wfc2  = (short*)(ws + 442368);
    float* battn = (float*)(ws + 589824);
    float* bhp   = (float*)(ws + 688128);
    float* bfc1p = (float*)(ws + 690432);

    k_prep<<<256, 256, 0, stream>>>(qkv_w, qkv_b, proj_w, fc1_w, fc1_b, fc2_w, rpb,
                                    Whead, Wproj, Wfc1, Wfc2, battn, bhp, bfc1p);
    k_fused<<<4096, 384, 0, stream>>>(x, ln1g, ln1b, Whead, bhp, Wproj, proj_b, battn,
                                      ln2g, ln2b, Wfc1, bfc1p, Wfc2, fc2_b, out);
}

// Round 6
// 664.096 us; speedup vs baseline: 1.4019x; 1.0592x over previous
//
#include <hip/hip_runtime.h>
#include <hip/hip_bf16.h>

// Swin block fused: C=180, NH=6, HD=30, WS=8, SS=4, N=64, B=16, H=W=128.
typedef short s16x8 __attribute__((ext_vector_type(8)));
typedef short s16x4 __attribute__((ext_vector_type(4)));
typedef float f32x4 __attribute__((ext_vector_type(4)));

__device__ __forceinline__ short f2bf(float f) {
    __bf16 h = (__bf16)f;
    return __builtin_bit_cast(short, h);
}
__device__ __forceinline__ float bf2f(short s) {
    return __builtin_bit_cast(float, ((unsigned int)(unsigned short)s) << 16);
}
__device__ __forceinline__ f32x4 mfma16(s16x8 a, s16x8 b, f32x4 c) {
    return __builtin_amdgcn_mfma_f32_16x16x32_bf16(a, b, c, 0, 0, 0);
}
// 8-byte-aligned b128 substitute (two ds_read_b64) for stride-36 rows
__device__ __forceinline__ s16x8 ld_b64x2(const short* p) {
    union { s16x8 v; s16x4 h[2]; } u;
    u.h[0] = *(const s16x4*)p;
    u.h[1] = *(const s16x4*)(p + 4);
    return u.v;
}

#define SCALE_Q 0.18257418583505536f

// ---------------- workspace layout (bytes) ----------------
// Whead bf16 [6][96][192] @ 0       rows: 0-31 q(scaled), 32-63 k, 64-95 v (hd pad 32)
// Wproj bf16 [192][192]   @ 221184
// Wfc1  bf16 [384][192]   @ 294912
// Wfc2  bf16 [192][384]   @ 442368
// battn bf16 [6][64(m)][64(n)] @ 589824  (TRANSPOSED: m-major)
// bh    f32  [6][96]      @ 638976
// bfc1  f32  [384]        @ 641280   total 642816

__global__ void k_prep(const float* __restrict__ qkv_w, const float* __restrict__ qkv_b,
                       const float* __restrict__ proj_w,
                       const float* __restrict__ fc1_w, const float* __restrict__ fc1_b,
                       const float* __restrict__ fc2_w,
                       const float* __restrict__ rpb,
                       short* __restrict__ Whead, short* __restrict__ Wproj,
                       short* __restrict__ Wfc1, short* __restrict__ Wfc2,
                       short* __restrict__ battn, float* __restrict__ bh,
                       float* __restrict__ bfc1) {
    int gt = blockIdx.x * 256 + threadIdx.x;
    int stride = gridDim.x * 256;
    for (int idx = gt; idx < 6 * 96 * 192; idx += stride) {
        int h = idx / (96 * 192), rem = idx - h * 96 * 192;
        int rr = rem / 192, kk = rem - rr * 192;
        int seg = rr >> 5, hd = rr & 31;
        float val = 0.f;
        if (hd < 30 && kk < 180) {
            int ch = seg * 180 + h * 30 + hd;
            val = qkv_w[ch * 180 + kk];
            if (seg == 0) val *= SCALE_Q;
        }
        Whead[idx] = f2bf(val);
    }
    for (int idx = gt; idx < 6 * 96; idx += stride) {
        int h = idx / 96, rr = idx - h * 96;
        int seg = rr >> 5, hd = rr & 31;
        float val = 0.f;
        if (hd < 30) {
            int ch = seg * 180 + h * 30 + hd;
            val = qkv_b[ch];
            if (seg == 0) val *= SCALE_Q;
        }
        bh[idx] = val;
    }
    for (int idx = gt; idx < 192 * 192; idx += stride) {
        int rr = idx / 192, kk = idx - rr * 192;
        Wproj[idx] = (rr < 180 && kk < 180) ? f2bf(proj_w[rr * 180 + kk]) : (short)0;
    }
    for (int idx = gt; idx < 384 * 192; idx += stride) {
        int rr = idx / 192, kk = idx - rr * 192;
        Wfc1[idx] = (rr < 360 && kk < 180) ? f2bf(fc1_w[rr * 180 + kk]) : (short)0;
    }
    for (int idx = gt; idx < 384; idx += stride)
        bfc1[idx] = (idx < 360) ? fc1_b[idx] : 0.f;
    for (int idx = gt; idx < 192 * 384; idx += stride) {
        int rr = idx / 384, kk = idx - rr * 384;
        Wfc2[idx] = (rr < 180 && kk < 360) ? f2bf(fc2_w[rr * 360 + kk]) : (short)0;
    }
    // battn[h][m][n] = bias[h][n][m]  (bf16, transposed so n is contiguous)
    for (int idx = gt; idx < 6 * 64 * 64; idx += stride) {
        int h = idx >> 12, m = (idx >> 6) & 63, n = idx & 63;
        int r1 = n >> 3, c1 = n & 7, r2 = m >> 3, c2 = m & 7;
        int ridx = (r1 - r2 + 7) * 15 + (c1 - c2 + 7);
        battn[idx] = f2bf(rpb[ridx * 6 + h]);
    }
}

// ---------------- fully fused kernel ----------------
// 1 block/window, 384 thr = 6 waves, wave h owns head h.
// LDS 53248 B -> 3 WG/CU target:
//  region A @0     (25600): xln[64][200] -> xout[64][200] -> ylds[64][200] -> mo bf16
//  region B @25600 (27648): patches 6x4608 -> pout bf16 [64][200] -> hid bf16 [64][200]
__global__ __launch_bounds__(384, 5)
void k_fused(const float* __restrict__ x, const float* __restrict__ g1, const float* __restrict__ b1,
             const short* __restrict__ Whead, const float* __restrict__ bh,
             const short* __restrict__ Wproj, const float* __restrict__ projb,
             const short* __restrict__ battn,
             const float* __restrict__ g2, const float* __restrict__ b2,
             const short* __restrict__ Wfc1, const float* __restrict__ bfc1,
             const short* __restrict__ Wfc2, const float* __restrict__ fb2,
             float* __restrict__ out) {
    __shared__ __align__(16) char smem[53248];
    short* xln  = (short*)smem;               // [64][200]
    short* xout = (short*)smem;               // overlays xln (after staging done)
    short* ylds = (short*)smem;               // overlays xout (after proj A-reads)
    short* mo   = (short*)smem;               // overlays ylds (after fc1 done)
    short* regB = (short*)(smem + 25600);
    short* pout = regB;                       // bf16 [64][200]
    short* hid  = regB;                       // bf16 [64][200]

    const int tid = threadIdx.x;
    const int wv = tid >> 6, l = tid & 63, l15 = l & 15, lg = l >> 4;
    short* patch = regB + wv * 2304;          // 4608 B each
    const int wid = blockIdx.x;
    const int b = wid >> 8, win = wid & 255, wi = win >> 4, wj = win & 15;
    const bool edge = (wi == 15) || (wj == 15);
    const f32x4 vzero = {0.f, 0.f, 0.f, 0.f};

    const int t = tid >> 2, sub = tid & 3;
    size_t rowbase = 0;
    if (tid < 256) {
        const int r = t >> 3, c = t & 7;
        const int gi = (wi * 8 + r + 4) & 127, gj = (wj * 8 + c + 4) & 127;
        rowbase = ((size_t)b * 16384 + (size_t)gi * 128 + gj) * 180;
    }
    const float* xrow = x + rowbase;
    float* yrow = out + rowbase;

    // ---- P1: LN1 -> xln (waves 0-3); helpers zero xln pads ----
    if (tid < 256) {
        float4 v[12];
        float s1 = 0.f, s2 = 0.f;
#pragma unroll
        for (int m = 0; m < 12; ++m) {
            int jj = sub + 4 * m;
            if (jj < 45) {
                float4 t4 = *(const float4*)&xrow[4 * jj];
                v[m] = t4;
                s1 += t4.x + t4.y + t4.z + t4.w;
                s2 += t4.x * t4.x + t4.y * t4.y + t4.z * t4.z + t4.w * t4.w;
            }
        }
        s1 += __shfl_xor(s1, 1); s2 += __shfl_xor(s2, 1);
        s1 += __shfl_xor(s1, 2); s2 += __shfl_xor(s2, 2);
        const float mu = s1 * (1.f / 180.f);
        const float rstd = rsqrtf(s2 * (1.f / 180.f) - mu * mu + 1e-5f);
#pragma unroll
        for (int m = 0; m < 12; ++m) {
            int jj = sub + 4 * m;
            if (jj < 45) {
                float4 g4 = *(const float4*)&g1[4 * jj];
                float4 b4 = *(const float4*)&b1[4 * jj];
                s16x4 w;
                w[0] = f2bf((v[m].x - mu) * rstd * g4.x + b4.x);
                w[1] = f2bf((v[m].y - mu) * rstd * g4.y + b4.y);
                w[2] = f2bf((v[m].z - mu) * rstd * g4.z + b4.z);
                w[3] = f2bf((v[m].w - mu) * rstd * g4.w + b4.w);
                *(s16x4*)&xln[t * 200 + 4 * jj] = w;
            }
        }
    } else {
        for (int k = tid - 256; k < 64 * 12; k += 128) {
            int rr = k / 12, cc = k - rr * 12;
            xln[rr * 200 + 180 + cc] = 0;
        }
    }
    __syncthreads();   // B1: xln ready

    // ---- P2: per-wave head staging (Q,K,V through private patch) ----
    const short* Wh = Whead + wv * (96 * 192);
    const float* bhh = bh + wv * 96;

    auto stage = [&](int G, auto&& store) {
#pragma unroll
        for (int jl = 0; jl < 2; ++jl) {
            s16x8 bw[6];
#pragma unroll
            for (int ks = 0; ks < 6; ++ks)
                bw[ks] = *(const s16x8*)&Wh[(G * 32 + jl * 16 + l15) * 192 + ks * 32 + lg * 8];
            float bias = bhh[G * 32 + jl * 16 + l15];
#pragma unroll
            for (int i = 0; i < 4; ++i) {
                f32x4 acc = vzero;
#pragma unroll
                for (int ks = 0; ks < 6; ++ks) {
                    s16x8 afi = *(const s16x8*)&xln[(i * 16 + l15) * 200 + ks * 32 + lg * 8];
                    acc = mfma16(afi, bw[ks], acc);
                }
                store(i, jl, acc, bias);
            }
        }
    };

    // Q -> patch [64][36]
    stage(0, [&](int i, int jl, f32x4 acc, float bias) {
#pragma unroll
        for (int tt = 0; tt < 4; ++tt)
            patch[(i * 16 + lg * 4 + tt) * 36 + jl * 16 + l15] = f2bf(acc[tt] + bias);
    });
    s16x8 qf[4];
#pragma unroll
    for (int i = 0; i < 4; ++i) qf[i] = ld_b64x2(&patch[(i * 16 + l15) * 36 + lg * 8]);

    // K -> patch [64][36] (reuse)
    stage(1, [&](int i, int jl, f32x4 acc, float bias) {
#pragma unroll
        for (int tt = 0; tt < 4; ++tt)
            patch[(i * 16 + lg * 4 + tt) * 36 + jl * 16 + l15] = f2bf(acc[tt] + bias);
    });
    s16x8 kf[4];
#pragma unroll
    for (int j = 0; j < 4; ++j) kf[j] = ld_b64x2(&patch[(j * 16 + l15) * 36 + lg * 8]);

    // V -> patch transposed [32][72], packed u32 stores
    stage(2, [&](int i, int jl, f32x4 acc, float bias) {
        int hd = jl * 16 + l15;
        int tok0 = i * 16 + lg * 4;
        unsigned int w0 = (unsigned int)(unsigned short)f2bf(acc[0] + bias) |
                          ((unsigned int)(unsigned short)f2bf(acc[1] + bias) << 16);
        unsigned int w1 = (unsigned int)(unsigned short)f2bf(acc[2] + bias) |
                          ((unsigned int)(unsigned short)f2bf(acc[3] + bias) << 16);
        *(unsigned int*)&patch[hd * 72 + tok0] = w0;
        *(unsigned int*)&patch[hd * 72 + tok0 + 2] = w1;
    });
    s16x8 vf[2][2];
#pragma unroll
    for (int j2 = 0; j2 < 2; ++j2)
#pragma unroll
        for (int ksv = 0; ksv < 2; ++ksv)
            vf[j2][ksv] = *(const s16x8*)&patch[(j2 * 16 + l15) * 72 + ksv * 32 + lg * 8];

    __syncthreads();   // B_x: all xln reads done -> xout (region A) writable

    if (wv == 0) {     // zero xout pad cols 180..191
        for (int k = l; k < 64 * 12; k += 64) {
            int rr = k / 12, cc = k - rr * 12;
            xout[rr * 200 + 180 + cc] = 0;
        }
    }

    // ---- attention: scores + softmax + PV, P ping-pong in patch ----
    {
        const short* bb = battn + wv * 4096;
#pragma unroll
        for (int i = 0; i < 4; ++i) {
            f32x4 sc[4];
#pragma unroll
            for (int j = 0; j < 4; ++j) sc[j] = mfma16(qf[i], kf[j], vzero);
            float p[4][4];
#pragma unroll
            for (int j = 0; j < 4; ++j) {
                int m = j * 16 + l15;
                s16x4 bv = *(const s16x4*)&bb[m * 64 + i * 16 + lg * 4];
                int rm = m >> 3, cm = m & 7;
                int cnt_m = (wi == 15 ? ((rm >= 4) ? 2 : 1) : 0) * 3 + (wj == 15 ? ((cm >= 4) ? 2 : 1) : 0);
#pragma unroll
                for (int tt = 0; tt < 4; ++tt) {
                    int n = i * 16 + lg * 4 + tt;
                    float s = sc[j][tt] + bf2f(bv[tt]);
                    if (edge) {
                        int rn = n >> 3, cn = n & 7;
                        int cnt_n = (wi == 15 ? ((rn >= 4) ? 2 : 1) : 0) * 3 + (wj == 15 ? ((cn >= 4) ? 2 : 1) : 0);
                        if (cnt_n != cnt_m) s -= 100.f;
                    }
                    p[j][tt] = s;
                }
            }
            float sm[4];
#pragma unroll
            for (int tt = 0; tt < 4; ++tt) {
                float m0 = fmaxf(fmaxf(p[0][tt], p[1][tt]), fmaxf(p[2][tt], p[3][tt]));
                m0 = fmaxf(m0, __shfl_xor(m0, 1));
                m0 = fmaxf(m0, __shfl_xor(m0, 2));
                m0 = fmaxf(m0, __shfl_xor(m0, 4));
                m0 = fmaxf(m0, __shfl_xor(m0, 8));
                float s0 = 0.f;
#pragma unroll
                for (int j = 0; j < 4; ++j) { float e = __expf(p[j][tt] - m0); p[j][tt] = e; s0 += e; }
                s0 += __shfl_xor(s0, 1); s0 += __shfl_xor(s0, 2);
                s0 += __shfl_xor(s0, 4); s0 += __shfl_xor(s0, 8);
                sm[tt] = __builtin_amdgcn_rcpf(s0);
            }
            short* pb = patch + (i & 1) * 1152;   // ping-pong [16][72]
#pragma unroll
            for (int j = 0; j < 4; ++j)
#pragma unroll
                for (int tt = 0; tt < 4; ++tt)
                    pb[(lg * 4 + tt) * 72 + j * 16 + l15] = f2bf(p[j][tt] * sm[tt]);
            s16x8 pa0 = *(const s16x8*)&pb[l15 * 72 + lg * 8];
            s16x8 pa1 = *(const s16x8*)&pb[l15 * 72 + 32 + lg * 8];
            f32x4 ov0 = mfma16(pa0, vf[0][0], vzero);
            ov0 = mfma16(pa1, vf[0][1], ov0);
            f32x4 ov1 = mfma16(pa0, vf[1][0], vzero);
            ov1 = mfma16(pa1, vf[1][1], ov1);
            // xout rows i*16.., cols wv*30 + hd
#pragma unroll
            for (int tt = 0; tt < 4; ++tt)
                xout[(i * 16 + lg * 4 + tt) * 200 + wv * 30 + l15] = f2bf(ov0[tt]);
            if (l15 < 14) {
#pragma unroll
                for (int tt = 0; tt < 4; ++tt)
                    xout[(i * 16 + lg * 4 + tt) * 200 + wv * 30 + 16 + l15] = f2bf(ov1[tt]);
            }
        }
    }
    __syncthreads();   // B3: xout complete, patches dead

    // ---- P3: proj GEMM -> pout bf16 (region B) ----
    {
#pragma unroll
        for (int jl = 0; jl < 2; ++jl) {
            s16x8 bw[6];
#pragma unroll
            for (int ks = 0; ks < 6; ++ks)
                bw[ks] = *(const s16x8*)&Wproj[(wv * 32 + jl * 16 + l15) * 192 + ks * 32 + lg * 8];
            int cch = wv * 32 + jl * 16 + l15;
            float pbv = (cch < 180) ? projb[cch] : 0.f;
#pragma unroll
            for (int i = 0; i < 4; ++i) {
                f32x4 acc = vzero;
#pragma unroll
                for (int ks = 0; ks < 6; ++ks) {
                    s16x8 afi = *(const s16x8*)&xout[(i * 16 + l15) * 200 + ks * 32 + lg * 8];
                    acc = mfma16(afi, bw[ks], acc);
                }
                if (cch < 180) {
#pragma unroll
                    for (int tt = 0; tt < 4; ++tt)
                        pout[(i * 16 + lg * 4 + tt) * 200 + cch] = f2bf(acc[tt] + pbv);
                }
            }
        }
    }
    __syncthreads();   // B4: pout ready, xout dead

    // ---- P4: y = x + pout -> d_out (f32) ; LN2 -> ylds ----
    if (tid < 256) {
        float4 yv[12];
        float s1 = 0.f, s2 = 0.f;
#pragma unroll
        for (int m = 0; m < 12; ++m) {
            int jj = sub + 4 * m;
            if (jj < 45) {
                float4 x4 = *(const float4*)&xrow[4 * jj];
                s16x4 pv = *(const s16x4*)&pout[t * 200 + 4 * jj];
                float4 y4;
                y4.x = x4.x + bf2f(pv[0]); y4.y = x4.y + bf2f(pv[1]);
                y4.z = x4.z + bf2f(pv[2]); y4.w = x4.w + bf2f(pv[3]);
                yv[m] = y4;
                *(float4*)&yrow[4 * jj] = y4;
                s1 += y4.x + y4.y + y4.z + y4.w;
                s2 += y4.x * y4.x + y4.y * y4.y + y4.z * y4.z + y4.w * y4.w;
            }
        }
        s1 += __shfl_xor(s1, 1); s2 += __shfl_xor(s2, 1);
        s1 += __shfl_xor(s1, 2); s2 += __shfl_xor(s2, 2);
        const float mu = s1 * (1.f / 180.f);
        const float rstd = rsqrtf(s2 * (1.f / 180.f) - mu * mu + 1e-5f);
#pragma unroll
        for (int m = 0; m < 12; ++m) {
            int jj = sub + 4 * m;
            if (jj < 45) {
                float4 g4 = *(const float4*)&g2[4 * jj];
                float4 b4 = *(const float4*)&b2[4 * jj];
                s16x4 w;
                w[0] = f2bf((yv[m].x - mu) * rstd * g4.x + b4.x);
                w[1] = f2bf((yv[m].y - mu) * rstd * g4.y + b4.y);
                w[2] = f2bf((yv[m].z - mu) * rstd * g4.z + b4.z);
                w[3] = f2bf((yv[m].w - mu) * rstd * g4.w + b4.w);
                *(s16x4*)&ylds[t * 200 + 4 * jj] = w;
            }
        }
    } else {
        for (int k = tid - 256; k < 64 * 12; k += 128) {
            int rr = k / 12, cc = k - rr * 12;
            ylds[rr * 200 + 180 + cc] = 0;
        }
    }
    __syncthreads();   // B5: ylds ready, pout dead

    // ---- P5: MLP (fc1+GELU per K-half, fc2 accumulated) ----
    f32x4 acc3[2][4];
#pragma unroll
    for (int jl = 0; jl < 2; ++jl)
#pragma unroll
        for (int i = 0; i < 4; ++i) acc3[jl][i] = vzero;

#pragma unroll
    for (int kh = 0; kh < 2; ++kh) {
#pragma unroll
        for (int jl = 0; jl < 2; ++jl) {
            s16x8 bw[6];
#pragma unroll
            for (int ks = 0; ks < 6; ++ks)
                bw[ks] = *(const s16x8*)&Wfc1[((kh * 12 + wv * 2 + jl) * 16 + l15) * 192 + ks * 32 + lg * 8];
            int cl = (wv * 2 + jl) * 16 + l15;
            float bv = bfc1[kh * 192 + cl];
#pragma unroll
            for (int i = 0; i < 4; ++i) {
                f32x4 acc = vzero;
#pragma unroll
                for (int ks = 0; ks < 6; ++ks) {
                    s16x8 ai = *(const s16x8*)&ylds[(i * 16 + l15) * 200 + ks * 32 + lg * 8];
                    acc = mfma16(ai, bw[ks], acc);
                }
#pragma unroll
                for (int tt = 0; tt < 4; ++tt) {
                    float v = acc[tt] + bv;
                    // gelu(v) ~= v * sigmoid(1.5957691*(v + 0.044715 v^3)); max err ~3e-4
                    float u = v * (1.f + 0.044715f * v * v);
                    float e = __expf(-1.5957691216f * u);
                    float gl = v * __builtin_amdgcn_rcpf(1.f + e);
                    hid[(i * 16 + lg * 4 + tt) * 200 + cl] = f2bf(gl);
                }
            }
        }
        __syncthreads();   // hid(kh) ready
#pragma unroll
        for (int ks = 0; ks < 6; ++ks) {
            s16x8 a[4];
#pragma unroll
            for (int i = 0; i < 4; ++i)
                a[i] = *(const s16x8*)&hid[(i * 16 + l15) * 200 + ks * 32 + lg * 8];
#pragma unroll
            for (int jl = 0; jl < 2; ++jl) {
                s16x8 bw2 = *(const s16x8*)&Wfc2[((wv * 2 + jl) * 16 + l15) * 384 + kh * 192 + ks * 32 + lg * 8];
#pragma unroll
                for (int i = 0; i < 4; ++i) acc3[jl][i] = mfma16(a[i], bw2, acc3[jl][i]);
            }
        }
        __syncthreads();   // hid consumed
    }

    // ---- fc2 out -> mo bf16 (region A; ylds dead) ----
#pragma unroll
    for (int jl = 0; jl < 2; ++jl) {
        int cch = (wv * 2 + jl) * 16 + l15;
        if (cch < 180) {
            float bv = fb2[cch];
#pragma unroll
            for (int i = 0; i < 4; ++i)
#pragma unroll
                for (int tt = 0; tt < 4; ++tt)
                    mo[(i * 16 + lg * 4 + tt) * 200 + cch] = f2bf(acc3[jl][i][tt] + bv);
        }
    }
    __syncthreads();   // B6: mo ready

    // ---- final: out = y + mlp ----
    if (tid < 256) {
#pragma unroll
        for (int m = 0; m < 12; ++m) {
            int jj = sub + 4 * m;
            if (jj < 45) {
                float4 y4 = *(const float4*)&yrow[4 * jj];
                s16x4 mv = *(const s16x4*)&mo[t * 200 + 4 * jj];
                float4 o;
                o.x = y4.x + bf2f(mv[0]); o.y = y4.y + bf2f(mv[1]);
                o.z = y4.z + bf2f(mv[2]); o.w = y4.w + bf2f(mv[3]);
                *(float4*)&yrow[4 * jj] = o;
            }
        }
    }
}

extern "C" void kernel_launch(void* const* d_in, const int* in_sizes, int n_in,
                              void* d_out, int out_size, void* d_ws, size_t ws_size,
                              hipStream_t stream) {
    (void)in_sizes; (void)n_in; (void)out_size; (void)ws_size;
    const float* x      = (const float*)d_in[0];
    const float* ln1g   = (const float*)d_in[1];
    const float* ln1b   = (const float*)d_in[2];
    const float* qkv_w  = (const float*)d_in[3];
    const float* qkv_b  = (const float*)d_in[4];
    const float* proj_w = (const float*)d_in[5];
    const float* proj_b = (const float*)d_in[6];
    const float* rpb    = (const float*)d_in[7];
    const float* ln2g   = (const float*)d_in[8];
    const float* ln2b   = (const float*)d_in[9];
    const float* fc1_w  = (const float*)d_in[10];
    const float* fc1_b  = (const float*)d_in[11];
    const float* fc2_w  = (const float*)d_in[12];
    const float* fc2_b  = (const float*)d_in[13];
    float* out = (float*)d_out;

    char* ws = (char*)d_ws;
    short* Whead = (short*)(ws + 0);
    short* Wproj = (short*)(ws + 221184);
    short* Wfc1  = (short*)(ws + 294912);
    short* Wfc2  = (short*)(ws + 442368);
    short* battn = (short*)(ws + 589824);
    float* bhp   = (float*)(ws + 638976);
    float* bfc1p = (float*)(ws + 641280);

    k_prep<<<256, 256, 0, stream>>>(qkv_w, qkv_b, proj_w, fc1_w, fc1_b, fc2_w, rpb,
                                    Whead, Wproj, Wfc1, Wfc2, battn, bhp, bfc1p);
    k_fused<<<4096, 384, 0, stream>>>(x, ln1g, ln1b, Whead, bhp, Wproj, proj_b, battn,
                                      ln2g, ln2b, Wfc1, bfc1p, Wfc2, fc2_b, out);
}